// Round 5
// baseline (62.626 us; speedup 1.0000x reference)
//
#include <hip/hip_runtime.h>
#include <math.h>

#define D 256
#define TWOD 512
#define BB 1024
#define NN 131072
#define LOG2E 1.4426950408889634f

typedef float v4f __attribute__((ext_vector_type(4)));

__device__ __forceinline__ v4f ldg_nt(const float* p, bool valid) {
  v4f z = {0.f, 0.f, 0.f, 0.f};
  if (valid) z = __builtin_nontemporal_load((const v4f*)p);
  return z;
}

__device__ __forceinline__ float dot4(v4f a, v4f b) {
  return fmaf(a.w, b.w, fmaf(a.z, b.z, fmaf(a.y, b.y, a.x * b.x)));
}

// butterfly pack: lane with rot r ends with full sum of row (base + r)
__device__ __forceinline__ float pack4(float d0, float d1, float d2, float d3) {
  float a01 = d0 + __shfl_xor(d1, 4);
  float a23 = d2 + __shfl_xor(d3, 4);
  float s = a01 + __shfl_xor(a23, 8);
  s += __shfl_xor(s, 1);
  s += __shfl_xor(s, 2);
  s += __shfl_xor(s, 16);
  s += __shfl_xor(s, 32);
  return s;
}

// ---------------- A: kq (blocks 0..255) + WvT (256..271) + WoT (272..303) + offs (304..815)
__global__ __launch_bounds__(256) void a_kernel(
    const float* __restrict__ V, const float* __restrict__ Wq,
    const float* __restrict__ Wk, const float* __restrict__ bq,
    const float* __restrict__ Wv, const float* __restrict__ Wo,
    const int* __restrict__ bidx,
    float* __restrict__ qt, float* __restrict__ WvT,
    float* __restrict__ WoT, int* __restrict__ offs) {
  __shared__ __align__(16) char smem[24576];
  const int blk = blockIdx.x;
  const int t = threadIdx.x;

  if (blk < 256) {
    // ---- kq: qt[b] = Wk^T (Wq V[b] + bq), 4 batches/block
    float* Vs   = (float*)smem;            // [4][256]
    float* q1s4 = (float*)(smem + 4096);   // [256][4]
    float* part = (float*)(smem + 8192);   // [4 waves][4 batches][256]
    const int wq = t >> 6, lane = t & 63;
    const int b0 = blk * 4;
    for (int i = 0; i < 4; ++i) Vs[i * 256 + t] = V[(size_t)(b0 + i) * D + t];
    __syncthreads();
    const int rot = (lane >> 2) & 3;
    const v4f vb0 = *(const v4f*)&Vs[0 * 256 + lane * 4];
    const v4f vb1 = *(const v4f*)&Vs[1 * 256 + lane * 4];
    const v4f vb2 = *(const v4f*)&Vs[2 * 256 + lane * 4];
    const v4f vb3 = *(const v4f*)&Vs[3 * 256 + lane * 4];

    // stage 1: q1 = Wq V (rotated rows, butterfly reduce)
    for (int ii = 0; ii < 16; ++ii) {
      const int cb = wq * 64 + ii * 4;
      const v4f r0 = *(const v4f*)(Wq + (size_t)(cb + (rot ^ 0)) * D + lane * 4);
      const v4f r1 = *(const v4f*)(Wq + (size_t)(cb + (rot ^ 1)) * D + lane * 4);
      const v4f r2 = *(const v4f*)(Wq + (size_t)(cb + (rot ^ 2)) * D + lane * 4);
      const v4f r3 = *(const v4f*)(Wq + (size_t)(cb + (rot ^ 3)) * D + lane * 4);
      const float s0 = pack4(dot4(r0, vb0), dot4(r1, vb0), dot4(r2, vb0), dot4(r3, vb0));
      const float s1 = pack4(dot4(r0, vb1), dot4(r1, vb1), dot4(r2, vb1), dot4(r3, vb1));
      const float s2 = pack4(dot4(r0, vb2), dot4(r1, vb2), dot4(r2, vb2), dot4(r3, vb2));
      const float s3 = pack4(dot4(r0, vb3), dot4(r1, vb3), dot4(r2, vb3), dot4(r3, vb3));
      if (lane < 16 && (lane & 3) == 0) {
        v4f o = {s0, s1, s2, s3};
        *(v4f*)&q1s4[(cb + rot) * 4] = o;
      }
    }
    __syncthreads();

    // stage 2: qt = Wk^T (q1 + bq), wave covers k in [wq*64,+64)
    v4f a0 = {0.f, 0.f, 0.f, 0.f}, a1 = a0, a2 = a0, a3 = a0;
    const int kb = wq * 64;
    for (int kk = 0; kk < 64; ++kk) {
      const int k = kb + kk;
      const v4f w4 = *(const v4f*)(Wk + (size_t)k * D + lane * 4);
      const v4f q = *(const v4f*)&q1s4[k * 4];
      const float bqk = bq[k];
      a0 += w4 * (q.x + bqk);
      a1 += w4 * (q.y + bqk);
      a2 += w4 * (q.z + bqk);
      a3 += w4 * (q.w + bqk);
    }
    *(v4f*)&part[(wq * 4 + 0) * 256 + lane * 4] = a0;
    *(v4f*)&part[(wq * 4 + 1) * 256 + lane * 4] = a1;
    *(v4f*)&part[(wq * 4 + 2) * 256 + lane * 4] = a2;
    *(v4f*)&part[(wq * 4 + 3) * 256 + lane * 4] = a3;
    __syncthreads();
    #pragma unroll
    for (int b = 0; b < 4; ++b) {
      const float s = part[(0 * 4 + b) * 256 + t] + part[(1 * 4 + b) * 256 + t] +
                      part[(2 * 4 + b) * 256 + t] + part[(3 * 4 + b) * 256 + t];
      qt[(size_t)(b0 + b) * D + t] = s;
    }
  } else if (blk < 304) {
    // ---- transposes
    float (*tile)[65] = (float(*)[65])smem;
    const float* src; float* dst; int r0, c0, C;
    if (blk < 272) { int b = blk - 256; src = Wv; dst = WvT; C = 256; r0 = (b >> 2) * 64; c0 = (b & 3) * 64; }
    else           { int b = blk - 272; src = Wo; dst = WoT; C = 512; r0 = (b >> 3) * 64; c0 = (b & 7) * 64; }
    const int lane = t & 63, sr = t >> 6;
    #pragma unroll 4
    for (int rr = 0; rr < 16; ++rr) {
      const int r = rr * 4 + sr;
      tile[r][lane] = src[(size_t)(r0 + r) * C + c0 + lane];
    }
    __syncthreads();
    #pragma unroll 4
    for (int rr = 0; rr < 16; ++rr) {
      const int r = rr * 4 + sr;
      dst[(size_t)(c0 + r) * 256 + r0 + lane] = tile[lane][r];
    }
  } else {
    // ---- offs scatter: offs[b] = lower_bound(bidx, b)
    const int i = (blk - 304) * 256 + t;
    if (i >= NN) return;
    const int b1 = bidx[i];
    const int b2 = (i + 1 < NN) ? bidx[i + 1] : BB;
    if (i == 0) {
      for (int b = 0; b <= b1; ++b) offs[b] = 0;
    }
    for (int b = b1 + 1; b <= b2; ++b) offs[b] = i + 1;
  }
}

// ---------------- k1: flash pass, 4 one-wave blocks per batch
__global__ __launch_bounds__(64) void k1_kernel(
    const float* __restrict__ H, const float* __restrict__ qt,
    const int* __restrict__ offs,
    float* __restrict__ sP, float* __restrict__ mP, float* __restrict__ dP) {
  const int blk = blockIdx.x;
  const int b = blk >> 2, qq = blk & 3;
  const int lane = threadIdx.x;
  const int start = offs[b], end = offs[b + 1];
  const int cnt = end - start;
  const int step = (cnt + 3) >> 2;
  const int s0 = start + min(cnt, qq * step);
  const int e0 = start + min(cnt, (qq + 1) * step);
  if (s0 >= e0) {
    v4f z = {0.f, 0.f, 0.f, 0.f};
    *(v4f*)&sP[(size_t)blk * D + lane * 4] = z;
    if (lane == 0) { mP[blk] = -1e30f; dP[blk] = 0.f; }
    return;
  }
  const v4f q4 = *(const v4f*)(qt + (size_t)b * D + lane * 4);
  const float SC = 0.0625f * LOG2E;
  const int odd = lane & 1;

  float m = -1e30f, den = 0.f;
  v4f acc = {0.f, 0.f, 0.f, 0.f};

  int n = s0;
  v4f c0 = ldg_nt(H + (size_t)n * D + lane * 4, true);
  v4f c1 = ldg_nt(H + (size_t)(n + 1) * D + lane * 4, n + 1 < e0);
  while (n < e0) {
    v4f p0 = ldg_nt(H + (size_t)(n + 2) * D + lane * 4, n + 2 < e0);
    v4f p1 = ldg_nt(H + (size_t)(n + 3) * D + lane * 4, n + 3 < e0);

    const float d0 = dot4(c0, q4);
    const float d1 = dot4(c1, q4);
    const float mine = odd ? d1 : d0;
    const float oth  = odd ? d0 : d1;
    float s = mine + __shfl_xor(oth, 1);
    s += __shfl_xor(s, 2);
    s += __shfl_xor(s, 4);
    s += __shfl_xor(s, 8);
    s += __shfl_xor(s, 16);
    s += __shfl_xor(s, 32);
    // lane parity p holds full dot of row n+p
    const float sc = (n + odd < e0) ? s * SC : -1e30f;

    const float mm = fmaxf(sc, __shfl_xor(sc, 1));
    const float nm = fmaxf(m, mm);
    const float f = exp2f(m - nm);
    const float w = exp2f(sc - nm);
    const float wx = __shfl_xor(w, 1);
    const float wr0 = odd ? wx : w;
    const float wr1 = odd ? w : wx;
    den = fmaf(den, f, w + wx);
    acc = acc * f + c0 * wr0 + c1 * wr1;
    m = nm;

    c0 = p0; c1 = p1; n += 2;
  }

  *(v4f*)&sP[(size_t)blk * D + lane * 4] = acc;
  if (lane == 0) { mP[blk] = m; dP[blk] = den; }
}

// ---------------- k2: merge 4 partials -> sN ; H~ = Wv sN + bv ; out = Wo [V;H~] + bo
__global__ __launch_bounds__(512) void k2_kernel(
    const float* __restrict__ V, const float* __restrict__ WvT,
    const float* __restrict__ WoT, const float* __restrict__ bv,
    const float* __restrict__ bo, const float* __restrict__ sP,
    const float* __restrict__ mP, const float* __restrict__ dP,
    const int* __restrict__ offs, float* __restrict__ out) {
  __shared__ __align__(16) float part[4][8][D];   // 32 KB
  __shared__ __align__(16) float sN[D][8];        // 8 KB
  __shared__ __align__(16) float Us[TWOD][8];     // 16 KB
  const int t = threadIdx.x;
  const int wq = __builtin_amdgcn_readfirstlane(t >> 6);
  const int lane = t & 63;
  const int k4 = lane * 4;
  const int b0 = blockIdx.x * 8;

  // ---- phase 0: merge the four k1 quarters; stage V
  {
    const int d = t & 255, i0 = (t >> 8) * 4;
    #pragma unroll
    for (int j = 0; j < 4; ++j) {
      const int i = i0 + j;
      const int bb = b0 + i;
      float m0 = mP[4 * bb + 0], m1 = mP[4 * bb + 1];
      float m2 = mP[4 * bb + 2], m3 = mP[4 * bb + 3];
      const float M = fmaxf(fmaxf(m0, m1), fmaxf(m2, m3));
      const float f0 = exp2f(m0 - M), f1 = exp2f(m1 - M);
      const float f2 = exp2f(m2 - M), f3 = exp2f(m3 - M);
      const float Dn = dP[4 * bb + 0] * f0 + dP[4 * bb + 1] * f1 +
                       dP[4 * bb + 2] * f2 + dP[4 * bb + 3] * f3;
      const float inv = (Dn > 0.f) ? (1.f / Dn) : 0.f;
      sN[d][i] = (sP[(size_t)(4 * bb + 0) * D + d] * f0 +
                  sP[(size_t)(4 * bb + 1) * D + d] * f1 +
                  sP[(size_t)(4 * bb + 2) * D + d] * f2 +
                  sP[(size_t)(4 * bb + 3) * D + d] * f3) * inv;
      Us[d][i] = V[(size_t)bb * D + d];
    }
  }
  __syncthreads();

  v4f a[8];
  // ---- phase A: H~ partials, wave wq covers h in [wq*32,+32)
  #pragma unroll
  for (int i = 0; i < 8; ++i) a[i] = (v4f){0.f, 0.f, 0.f, 0.f};
  {
    const int hbase = wq * 32;
    for (int hh = 0; hh < 32; ++hh) {
      const int h = hbase + hh;
      const v4f w4 = *(const v4f*)(WvT + (size_t)h * D + k4);
      const v4f slo = *(const v4f*)&sN[h][0];
      const v4f shi = *(const v4f*)&sN[h][4];
      a[0] += w4 * slo.x; a[1] += w4 * slo.y; a[2] += w4 * slo.z; a[3] += w4 * slo.w;
      a[4] += w4 * shi.x; a[5] += w4 * shi.y; a[6] += w4 * shi.z; a[7] += w4 * shi.w;
    }
  }
  if (wq >= 4) {
    #pragma unroll
    for (int i = 0; i < 8; ++i) *(v4f*)&part[wq - 4][i][k4] = a[i];
  }
  __syncthreads();
  if (wq < 4) {
    #pragma unroll
    for (int i = 0; i < 8; ++i) {
      const v4f p = *(const v4f*)&part[wq][i][k4];
      *(v4f*)&part[wq][i][k4] = a[i] + p;
    }
  }
  __syncthreads();
  {
    const int d = t & 255, i0 = (t >> 8) * 4;
    #pragma unroll
    for (int j = 0; j < 4; ++j) {
      const int i = i0 + j;
      float s = bv[d];
      #pragma unroll
      for (int w = 0; w < 4; ++w) s += part[w][i][d];
      Us[D + d][i] = s;
    }
  }
  __syncthreads();

  // ---- phase B: out partials, wave wq covers k in [wq*64,+64)
  #pragma unroll
  for (int i = 0; i < 8; ++i) a[i] = (v4f){0.f, 0.f, 0.f, 0.f};
  {
    const int kbase = wq * 64;
    for (int kk = 0; kk < 64; ++kk) {
      const int k = kbase + kk;
      const v4f w4 = *(const v4f*)(WoT + (size_t)k * D + k4);
      const v4f ulo = *(const v4f*)&Us[k][0];
      const v4f uhi = *(const v4f*)&Us[k][4];
      a[0] += w4 * ulo.x; a[1] += w4 * ulo.y; a[2] += w4 * ulo.z; a[3] += w4 * ulo.w;
      a[4] += w4 * uhi.x; a[5] += w4 * uhi.y; a[6] += w4 * uhi.z; a[7] += w4 * uhi.w;
    }
  }
  if (wq >= 4) {
    #pragma unroll
    for (int i = 0; i < 8; ++i) *(v4f*)&part[wq - 4][i][k4] = a[i];
  }
  __syncthreads();
  if (wq < 4) {
    #pragma unroll
    for (int i = 0; i < 8; ++i) {
      const v4f p = *(const v4f*)&part[wq][i][k4];
      *(v4f*)&part[wq][i][k4] = a[i] + p;
    }
  }
  __syncthreads();
  {
    const int d = t & 255, i0 = (t >> 8) * 4;
    #pragma unroll
    for (int j = 0; j < 4; ++j) {
      const int i = i0 + j;
      const int bb = b0 + i;
      float s = bo[d];
      #pragma unroll
      for (int w = 0; w < 4; ++w) s += part[w][i][d];
      const int c = offs[bb + 1] - offs[bb];
      out[(size_t)bb * D + d] = (c > 0) ? s : Us[d][i];
    }
  }
}

extern "C" void kernel_launch(void* const* d_in, const int* in_sizes, int n_in,
                              void* d_out, int out_size, void* d_ws, size_t ws_size,
                              hipStream_t stream) {
  const float* V   = (const float*)d_in[0];
  const float* H   = (const float*)d_in[1];
  const int* bidx  = (const int*)d_in[2];
  const float* Wq  = (const float*)d_in[3];
  const float* bq  = (const float*)d_in[4];
  const float* Wk  = (const float*)d_in[5];
  const float* Wv  = (const float*)d_in[7];
  const float* bv  = (const float*)d_in[8];
  const float* Wo  = (const float*)d_in[9];
  const float* bo  = (const float*)d_in[10];
  float* out = (float*)d_out;

  float* ws  = (float*)d_ws;
  float* WvT = ws;                       // 256*256
  float* WoT = WvT + D * D;              // 512*256
  float* qt  = WoT + TWOD * D;           // 1024*256
  float* sP  = qt + BB * D;              // 4096*256
  float* mP  = sP + 4 * BB * D;          // 4096
  float* dP  = mP + 4 * BB;              // 4096
  int* offs  = (int*)(dP + 4 * BB);      // 1025

  hipLaunchKernelGGL(a_kernel, dim3(816), dim3(256), 0, stream,
                     V, Wq, Wk, bq, Wv, Wo, bidx, qt, WvT, WoT, offs);
  hipLaunchKernelGGL(k1_kernel, dim3(4 * BB), dim3(64), 0, stream,
                     H, qt, offs, sP, mP, dP);
  hipLaunchKernelGGL(k2_kernel, dim3(BB / 8), dim3(512), 0, stream,
                     V, WvT, WoT, bv, bo, sP, mP, dP, offs, out);
}

// Round 6
// 53.147 us; speedup vs baseline: 1.1784x; 1.1784x over previous
//
#include <hip/hip_runtime.h>
#include <math.h>

#define D 256
#define TWOD 512
#define BB 1024
#define NN 131072
#define LOG2E 1.4426950408889634f

typedef float v4f __attribute__((ext_vector_type(4)));

__device__ __forceinline__ v4f ldg_nt(const float* p, bool valid) {
  v4f z = {0.f, 0.f, 0.f, 0.f};
  if (valid) z = __builtin_nontemporal_load((const v4f*)p);
  return z;
}

__device__ __forceinline__ float dot4(v4f a, v4f b) {
  return fmaf(a.w, b.w, fmaf(a.z, b.z, fmaf(a.y, b.y, a.x * b.x)));
}

// butterfly pack: lane with rot r ends with full sum of row (base + r)
__device__ __forceinline__ float pack4(float d0, float d1, float d2, float d3) {
  float a01 = d0 + __shfl_xor(d1, 4);
  float a23 = d2 + __shfl_xor(d3, 4);
  float s = a01 + __shfl_xor(a23, 8);
  s += __shfl_xor(s, 1);
  s += __shfl_xor(s, 2);
  s += __shfl_xor(s, 16);
  s += __shfl_xor(s, 32);
  return s;
}

// ---------------- A: kq (blocks 0..255) + WvT (256..271) + WoT (272..303) + offs (304..815)
__global__ __launch_bounds__(256) void a_kernel(
    const float* __restrict__ V, const float* __restrict__ Wq,
    const float* __restrict__ Wk, const float* __restrict__ bq,
    const float* __restrict__ Wv, const float* __restrict__ Wo,
    const int* __restrict__ bidx,
    float* __restrict__ qt, float* __restrict__ WvT,
    float* __restrict__ WoT, int* __restrict__ offs) {
  __shared__ __align__(16) char smem[24576];
  const int blk = blockIdx.x;
  const int t = threadIdx.x;

  if (blk < 256) {
    // ---- kq: qt[b] = Wk^T (Wq V[b] + bq), 4 batches/block
    float* Vs   = (float*)smem;            // [4][256]
    float* q1s4 = (float*)(smem + 4096);   // [256][4]
    float* part = (float*)(smem + 8192);   // [4 waves][4 batches][256]
    const int wq = t >> 6, lane = t & 63;
    const int b0 = blk * 4;
    for (int i = 0; i < 4; ++i) Vs[i * 256 + t] = V[(size_t)(b0 + i) * D + t];
    __syncthreads();
    const int rot = (lane >> 2) & 3;
    const v4f vb0 = *(const v4f*)&Vs[0 * 256 + lane * 4];
    const v4f vb1 = *(const v4f*)&Vs[1 * 256 + lane * 4];
    const v4f vb2 = *(const v4f*)&Vs[2 * 256 + lane * 4];
    const v4f vb3 = *(const v4f*)&Vs[3 * 256 + lane * 4];

    // stage 1: q1 = Wq V (rotated rows, butterfly reduce)
    for (int ii = 0; ii < 16; ++ii) {
      const int cb = wq * 64 + ii * 4;
      const v4f r0 = *(const v4f*)(Wq + (size_t)(cb + (rot ^ 0)) * D + lane * 4);
      const v4f r1 = *(const v4f*)(Wq + (size_t)(cb + (rot ^ 1)) * D + lane * 4);
      const v4f r2 = *(const v4f*)(Wq + (size_t)(cb + (rot ^ 2)) * D + lane * 4);
      const v4f r3 = *(const v4f*)(Wq + (size_t)(cb + (rot ^ 3)) * D + lane * 4);
      const float s0 = pack4(dot4(r0, vb0), dot4(r1, vb0), dot4(r2, vb0), dot4(r3, vb0));
      const float s1 = pack4(dot4(r0, vb1), dot4(r1, vb1), dot4(r2, vb1), dot4(r3, vb1));
      const float s2 = pack4(dot4(r0, vb2), dot4(r1, vb2), dot4(r2, vb2), dot4(r3, vb2));
      const float s3 = pack4(dot4(r0, vb3), dot4(r1, vb3), dot4(r2, vb3), dot4(r3, vb3));
      if (lane < 16 && (lane & 3) == 0) {
        v4f o = {s0, s1, s2, s3};
        *(v4f*)&q1s4[(cb + rot) * 4] = o;
      }
    }
    __syncthreads();

    // stage 2: qt = Wk^T (q1 + bq), wave covers k in [wq*64,+64)
    v4f a0 = {0.f, 0.f, 0.f, 0.f}, a1 = a0, a2 = a0, a3 = a0;
    const int kb = wq * 64;
    for (int kk = 0; kk < 64; ++kk) {
      const int k = kb + kk;
      const v4f w4 = *(const v4f*)(Wk + (size_t)k * D + lane * 4);
      const v4f q = *(const v4f*)&q1s4[k * 4];
      const float bqk = bq[k];
      a0 += w4 * (q.x + bqk);
      a1 += w4 * (q.y + bqk);
      a2 += w4 * (q.z + bqk);
      a3 += w4 * (q.w + bqk);
    }
    *(v4f*)&part[(wq * 4 + 0) * 256 + lane * 4] = a0;
    *(v4f*)&part[(wq * 4 + 1) * 256 + lane * 4] = a1;
    *(v4f*)&part[(wq * 4 + 2) * 256 + lane * 4] = a2;
    *(v4f*)&part[(wq * 4 + 3) * 256 + lane * 4] = a3;
    __syncthreads();
    #pragma unroll
    for (int b = 0; b < 4; ++b) {
      const float s = part[(0 * 4 + b) * 256 + t] + part[(1 * 4 + b) * 256 + t] +
                      part[(2 * 4 + b) * 256 + t] + part[(3 * 4 + b) * 256 + t];
      qt[(size_t)(b0 + b) * D + t] = s;
    }
  } else if (blk < 304) {
    // ---- transposes
    float (*tile)[65] = (float(*)[65])smem;
    const float* src; float* dst; int r0, c0, C;
    if (blk < 272) { int b = blk - 256; src = Wv; dst = WvT; C = 256; r0 = (b >> 2) * 64; c0 = (b & 3) * 64; }
    else           { int b = blk - 272; src = Wo; dst = WoT; C = 512; r0 = (b >> 3) * 64; c0 = (b & 7) * 64; }
    const int lane = t & 63, sr = t >> 6;
    #pragma unroll 4
    for (int rr = 0; rr < 16; ++rr) {
      const int r = rr * 4 + sr;
      tile[r][lane] = src[(size_t)(r0 + r) * C + c0 + lane];
    }
    __syncthreads();
    #pragma unroll 4
    for (int rr = 0; rr < 16; ++rr) {
      const int r = rr * 4 + sr;
      dst[(size_t)(c0 + r) * 256 + r0 + lane] = tile[lane][r];
    }
  } else {
    // ---- offs scatter: offs[b] = lower_bound(bidx, b)
    const int i = (blk - 304) * 256 + t;
    if (i >= NN) return;
    const int b1 = bidx[i];
    const int b2 = (i + 1 < NN) ? bidx[i + 1] : BB;
    if (i == 0) {
      for (int b = 0; b <= b1; ++b) offs[b] = 0;
    }
    for (int b = b1 + 1; b <= b2; ++b) offs[b] = i + 1;
  }
}

// ---------------- fused: flash (per-wave quarter) + merge + H~ + out, 4 batches/block
__global__ __launch_bounds__(1024) void f_kernel(
    const float* __restrict__ H, const float* __restrict__ qt,
    const int* __restrict__ offs, const float* __restrict__ V,
    const float* __restrict__ WvT, const float* __restrict__ WoT,
    const float* __restrict__ bv, const float* __restrict__ bo,
    float* __restrict__ out) {
  __shared__ __align__(16) float ss[16][D];       // 16 KB flash staging
  __shared__ float sm[16], sd[16];
  __shared__ __align__(16) float sN2[D][4];       // 4 KB  [h][batch]
  __shared__ __align__(16) float Us2[TWOD][4];    // 8 KB  [k][batch]
  __shared__ __align__(16) float part[8][4][D];   // 32 KB

  const int t = threadIdx.x;
  const int wave = t >> 6, lane = t & 63;
  const int blk = blockIdx.x;
  const int ib = wave >> 2, qq = wave & 3;
  const int bb = blk * 4 + ib;

  const int start = offs[bb], end = offs[bb + 1];
  const int cnt = end - start;
  const int step = (cnt + 3) >> 2;
  const int s0 = start + min(cnt, qq * step);
  const int e0 = start + min(cnt, (qq + 1) * step);

  float m = -1e30f, den = 0.f;
  v4f acc = {0.f, 0.f, 0.f, 0.f};

  if (s0 < e0) {
    const v4f q4 = *(const v4f*)(qt + (size_t)bb * D + lane * 4);
    const float SC = 0.0625f * LOG2E;
    const int odd = lane & 1;
    int n = s0;
    v4f c0 = ldg_nt(H + (size_t)n * D + lane * 4, true);
    v4f c1 = ldg_nt(H + (size_t)(n + 1) * D + lane * 4, n + 1 < e0);
    while (n < e0) {
      v4f p0 = ldg_nt(H + (size_t)(n + 2) * D + lane * 4, n + 2 < e0);
      v4f p1 = ldg_nt(H + (size_t)(n + 3) * D + lane * 4, n + 3 < e0);

      const float d0 = dot4(c0, q4);
      const float d1 = dot4(c1, q4);
      const float mine = odd ? d1 : d0;
      const float oth  = odd ? d0 : d1;
      float s = mine + __shfl_xor(oth, 1);
      s += __shfl_xor(s, 2);
      s += __shfl_xor(s, 4);
      s += __shfl_xor(s, 8);
      s += __shfl_xor(s, 16);
      s += __shfl_xor(s, 32);
      const float sc = (n + odd < e0) ? s * SC : -1e30f;

      const float mm = fmaxf(sc, __shfl_xor(sc, 1));
      const float nm = fmaxf(m, mm);
      const float f = exp2f(m - nm);
      const float w = exp2f(sc - nm);
      const float wx = __shfl_xor(w, 1);
      const float wr0 = odd ? wx : w;
      const float wr1 = odd ? w : wx;
      den = fmaf(den, f, w + wx);
      acc = acc * f + c0 * wr0 + c1 * wr1;
      m = nm;

      c0 = p0; c1 = p1; n += 2;
    }
  }
  *(v4f*)&ss[wave][lane * 4] = acc;
  if (lane == 0) { sm[wave] = m; sd[wave] = den; }
  __syncthreads();

  // ---- merge 4 quarters per batch -> sN2; stage V
  {
    const int i = t >> 8, d = t & 255;
    const int w0 = i * 4;
    const float m0 = sm[w0], m1 = sm[w0 + 1], m2 = sm[w0 + 2], m3 = sm[w0 + 3];
    const float M = fmaxf(fmaxf(m0, m1), fmaxf(m2, m3));
    const float f0 = exp2f(m0 - M), f1 = exp2f(m1 - M);
    const float f2 = exp2f(m2 - M), f3 = exp2f(m3 - M);
    const float Dn = sd[w0] * f0 + sd[w0 + 1] * f1 + sd[w0 + 2] * f2 + sd[w0 + 3] * f3;
    const float inv = (Dn > 0.f) ? (1.f / Dn) : 0.f;
    sN2[d][i] = (ss[w0][d] * f0 + ss[w0 + 1][d] * f1 +
                 ss[w0 + 2][d] * f2 + ss[w0 + 3][d] * f3) * inv;
    Us2[d][i] = V[(size_t)(blk * 4 + i) * D + d];
  }
  __syncthreads();

  // ---- phase A: H~ partials, wave covers h in [wave*16,+16)
  v4f a0 = {0.f, 0.f, 0.f, 0.f}, a1 = a0, a2 = a0, a3 = a0;
  {
    const int hb = wave * 16;
    #pragma unroll 4
    for (int hh = 0; hh < 16; ++hh) {
      const int h = hb + hh;
      const v4f w4 = *(const v4f*)(WvT + (size_t)h * D + lane * 4);
      const v4f s4 = *(const v4f*)&sN2[h][0];      // b128 broadcast
      a0 += w4 * s4.x; a1 += w4 * s4.y; a2 += w4 * s4.z; a3 += w4 * s4.w;
    }
  }
  if (wave >= 8) {
    *(v4f*)&part[wave - 8][0][lane * 4] = a0;
    *(v4f*)&part[wave - 8][1][lane * 4] = a1;
    *(v4f*)&part[wave - 8][2][lane * 4] = a2;
    *(v4f*)&part[wave - 8][3][lane * 4] = a3;
  }
  __syncthreads();
  if (wave < 8) {
    v4f p0 = *(const v4f*)&part[wave][0][lane * 4];
    v4f p1 = *(const v4f*)&part[wave][1][lane * 4];
    v4f p2 = *(const v4f*)&part[wave][2][lane * 4];
    v4f p3 = *(const v4f*)&part[wave][3][lane * 4];
    *(v4f*)&part[wave][0][lane * 4] = a0 + p0;
    *(v4f*)&part[wave][1][lane * 4] = a1 + p1;
    *(v4f*)&part[wave][2][lane * 4] = a2 + p2;
    *(v4f*)&part[wave][3][lane * 4] = a3 + p3;
  }
  __syncthreads();
  {
    const int i = t >> 8, d = t & 255;
    float s = bv[d];
    #pragma unroll
    for (int w = 0; w < 8; ++w) s += part[w][i][d];
    Us2[D + d][i] = s;
  }
  __syncthreads();

  // ---- phase B: out partials, wave covers k in [wave*32,+32)
  a0 = (v4f){0.f, 0.f, 0.f, 0.f}; a1 = a0; a2 = a0; a3 = a0;
  {
    const int kb = wave * 32;
    #pragma unroll 4
    for (int kk = 0; kk < 32; ++kk) {
      const int k = kb + kk;
      const v4f w4 = *(const v4f*)(WoT + (size_t)k * D + lane * 4);
      const v4f u4 = *(const v4f*)&Us2[k][0];      // b128 broadcast
      a0 += w4 * u4.x; a1 += w4 * u4.y; a2 += w4 * u4.z; a3 += w4 * u4.w;
    }
  }
  if (wave >= 8) {
    *(v4f*)&part[wave - 8][0][lane * 4] = a0;
    *(v4f*)&part[wave - 8][1][lane * 4] = a1;
    *(v4f*)&part[wave - 8][2][lane * 4] = a2;
    *(v4f*)&part[wave - 8][3][lane * 4] = a3;
  }
  __syncthreads();
  if (wave < 8) {
    v4f p0 = *(const v4f*)&part[wave][0][lane * 4];
    v4f p1 = *(const v4f*)&part[wave][1][lane * 4];
    v4f p2 = *(const v4f*)&part[wave][2][lane * 4];
    v4f p3 = *(const v4f*)&part[wave][3][lane * 4];
    *(v4f*)&part[wave][0][lane * 4] = a0 + p0;
    *(v4f*)&part[wave][1][lane * 4] = a1 + p1;
    *(v4f*)&part[wave][2][lane * 4] = a2 + p2;
    *(v4f*)&part[wave][3][lane * 4] = a3 + p3;
  }
  __syncthreads();
  {
    const int i = t >> 8, d = t & 255;
    const int bb2 = blk * 4 + i;
    float s = bo[d];
    #pragma unroll
    for (int w = 0; w < 8; ++w) s += part[w][i][d];
    const int c = offs[bb2 + 1] - offs[bb2];
    out[(size_t)bb2 * D + d] = (c > 0) ? s : Us2[d][i];
  }
}

extern "C" void kernel_launch(void* const* d_in, const int* in_sizes, int n_in,
                              void* d_out, int out_size, void* d_ws, size_t ws_size,
                              hipStream_t stream) {
  const float* V   = (const float*)d_in[0];
  const float* H   = (const float*)d_in[1];
  const int* bidx  = (const int*)d_in[2];
  const float* Wq  = (const float*)d_in[3];
  const float* bq  = (const float*)d_in[4];
  const float* Wk  = (const float*)d_in[5];
  const float* Wv  = (const float*)d_in[7];
  const float* bv  = (const float*)d_in[8];
  const float* Wo  = (const float*)d_in[9];
  const float* bo  = (const float*)d_in[10];
  float* out = (float*)d_out;

  float* ws  = (float*)d_ws;
  float* WvT = ws;                       // 256*256
  float* WoT = WvT + D * D;              // 512*256
  float* qt  = WoT + TWOD * D;           // 1024*256
  int* offs  = (int*)(qt + BB * D);      // 1025

  hipLaunchKernelGGL(a_kernel, dim3(816), dim3(256), 0, stream,
                     V, Wq, Wk, bq, Wv, Wo, bidx, qt, WvT, WoT, offs);
  hipLaunchKernelGGL(f_kernel, dim3(BB / 4), dim3(1024), 0, stream,
                     H, qt, offs, V, WvT, WoT, bv, bo, out);
}